// Round 7
// baseline (151.886 us; speedup 1.0000x reference)
//
#include <hip/hip_runtime.h>
#include <hip/hip_bf16.h>

#define N_NODES 100000
#define NODES_PAD 100096
#define N_ARCS 1000000

typedef __attribute__((ext_vector_type(8))) short bf16x8;
typedef __attribute__((ext_vector_type(4))) float f32x4;

__device__ __forceinline__ unsigned pk2(float lo, float hi) {
    __hip_bfloat162 b = __float22bfloat162_rn(make_float2(lo, hi));
    union { __hip_bfloat162 b; unsigned u; } c; c.b = b; return c.u;
}

__device__ __forceinline__ uint4 pack8(const float4 a, const float4 b) {
    uint4 r;
    r.x = pk2(a.x, a.y);
    r.y = pk2(a.z, a.w);
    r.z = pk2(b.x, b.y);
    r.w = pk2(b.z, b.w);
    return r;
}

// Persistent GEMM + fused int8 row quantization. B fragments live in VGPRs
// (loaded once per block); A tile double-buffered in LDS, 1 barrier/tile.
// y=0: U = z@W1[:,:128]^T + b1 ; y=1: V = z@W1[:,128:]^T.
// UVq rows byte-PERMUTED: byte p of 128-B half-row holds col (p&7)*16 + (p>>3).
__global__ __launch_bounds__(256, 2) void gemm_uv_q(const float* __restrict__ z,
                                                    const float* __restrict__ W1,
                                                    const float* __restrict__ b1,
                                                    unsigned char* __restrict__ UVq,
                                                    float* __restrict__ scl) {
    __shared__ unsigned char lds[49152];                       // 48 KB
    unsigned short* As0 = (unsigned short*)lds;                // 16 KB
    unsigned short* As1 = (unsigned short*)(lds + 16384);      // 16 KB (aliases Bs lo)
    unsigned short* Bs  = (unsigned short*)(lds + 16384);      // 32 KB (init only)

    const int tid = threadIdx.x;
    const int y = blockIdx.y;
    const int c0 = y * 128;
    const int lane = tid & 63;
    const int wave = tid >> 6;
    const int l16 = lane & 15;
    const int quad = lane >> 4;
    const int mstep = gridDim.x * 64;

    // --- one-time: stage W1-half to LDS (swizzled), plus first A tile ---
    #pragma unroll
    for (int it = 0; it < 8; it++) {
        int i = tid + it * 256;
        int row = i >> 4, g = i & 15;
        const float4* s = (const float4*)(W1 + (long)row * 256 + c0 + g * 8);
        ((uint4*)Bs)[row * 16 + (g ^ (row & 15))] = pack8(s[0], s[1]);
    }
    int m0 = blockIdx.x * 64;
    #pragma unroll
    for (int it = 0; it < 4; it++) {
        int i = tid + it * 256;
        int row = i >> 4, g = i & 15;
        int node = m0 + row;
        uint4 p = make_uint4(0u, 0u, 0u, 0u);
        if (node < N_NODES) {
            const float4* s = (const float4*)(z + (long)node * 128 + g * 8);
            p = pack8(s[0], s[1]);
        }
        ((uint4*)As0)[row * 16 + (g ^ (row & 15))] = p;
    }
    __syncthreads();

    // --- hoist B fragments into registers: breg[nt][ks] ---
    bf16x8 breg[8][4];
    #pragma unroll
    for (int nt = 0; nt < 8; nt++)
        #pragma unroll
        for (int ks = 0; ks < 4; ks++)
            breg[nt][ks] = *(const bf16x8*)&Bs[(nt * 16 + l16) * 128 +
                                               (((ks * 4 + quad) ^ l16) << 3)];
    __syncthreads();   // everyone done with Bs before As1 overwrites it

    float bias[8];
    #pragma unroll
    for (int nt = 0; nt < 8; nt++)
        bias[nt] = (y == 0) ? b1[nt * 16 + l16] : 0.0f;
    float* sclh = scl + (long)y * NODES_PAD;

    int t = 0;
    while (m0 < N_NODES) {
        const int m1 = m0 + mstep;
        unsigned short* cur = (t & 1) ? As1 : As0;
        unsigned short* nxt = (t & 1) ? As0 : As1;
        const bool have_next = m1 < N_NODES;

        // issue next tile's global loads early (latency hides under MFMA)
        float4 ld[8];
        if (have_next) {
            #pragma unroll
            for (int it = 0; it < 4; it++) {
                int i = tid + it * 256;
                int row = i >> 4, g = i & 15;
                int node = m1 + row;
                if (node < N_NODES) {
                    const float4* s = (const float4*)(z + (long)node * 128 + g * 8);
                    ld[it * 2] = s[0];
                    ld[it * 2 + 1] = s[1];
                } else {
                    ld[it * 2] = make_float4(0.f, 0.f, 0.f, 0.f);
                    ld[it * 2 + 1] = make_float4(0.f, 0.f, 0.f, 0.f);
                }
            }
        }

        // compute: 4 ds_read_b128 + 32 MFMA
        const int arow = wave * 16 + l16;
        f32x4 acc[8] = {};
        #pragma unroll
        for (int ks = 0; ks < 4; ks++) {
            const bf16x8 a = *(const bf16x8*)&cur[arow * 128 +
                                                  (((ks * 4 + quad) ^ l16) << 3)];
            #pragma unroll
            for (int nt = 0; nt < 8; nt++)
                acc[nt] = __builtin_amdgcn_mfma_f32_16x16x32_bf16(a, breg[nt][ks],
                                                                  acc[nt], 0, 0, 0);
        }

        // write next tile into the other LDS buffer
        if (have_next) {
            #pragma unroll
            for (int it = 0; it < 4; it++) {
                int i = tid + it * 256;
                int row = i >> 4, g = i & 15;
                ((uint4*)nxt)[row * 16 + (g ^ (row & 15))] =
                    pack8(ld[it * 2], ld[it * 2 + 1]);
            }
        }

        // epilogue: bias, row absmax (16-lane butterfly), quantize, packed store
        float m[4] = {0.f, 0.f, 0.f, 0.f};
        #pragma unroll
        for (int nt = 0; nt < 8; nt++)
            #pragma unroll
            for (int r = 0; r < 4; r++) {
                acc[nt][r] += bias[nt];
                m[r] = fmaxf(m[r], fabsf(acc[nt][r]));
            }
        #pragma unroll
        for (int o = 1; o <= 8; o <<= 1)
            #pragma unroll
            for (int r = 0; r < 4; r++)
                m[r] = fmaxf(m[r], __shfl_xor(m[r], o));

        const int rbase = m0 + wave * 16 + quad * 4;
        float inv[4];
        #pragma unroll
        for (int r = 0; r < 4; r++) {
            m[r] = fmaxf(m[r], 1e-30f);
            inv[r] = 127.0f * __builtin_amdgcn_rcpf(m[r]);
        }
        if (l16 == 0)
            *(float4*)(sclh + rbase) = make_float4(m[0] * (1.f / 127.f), m[1] * (1.f / 127.f),
                                                   m[2] * (1.f / 127.f), m[3] * (1.f / 127.f));
        #pragma unroll
        for (int r = 0; r < 4; r++) {
            unsigned lo = 0, hi = 0;
            #pragma unroll
            for (int nt = 0; nt < 4; nt++) {
                unsigned q = (unsigned)__float2int_rn(fmaf(acc[nt][r], inv[r], 128.f));
                lo |= (q & 0xffu) << (8 * nt);
            }
            #pragma unroll
            for (int nt = 4; nt < 8; nt++) {
                unsigned q = (unsigned)__float2int_rn(fmaf(acc[nt][r], inv[r], 128.f));
                hi |= (q & 0xffu) << (8 * (nt - 4));
            }
            *(uint2*)(UVq + (long)(rbase + r) * 256 + c0 + l16 * 8) = make_uint2(lo, hi);
        }
        __syncthreads();
        m0 = m1;
        t ^= 1;
    }
}

// One arc-pair per 8-lane group (uint4 = 16 elems/lane), software-pipelined.
// relu trick: out = sU*(sum_j max(h_j, C)*w2_j - C*sumW2) + b2,
// h_j = gu_j + r*gv_j, r = sV/sU, C = 128*(1+r).
__global__ __launch_bounds__(256) void arc_score(const int4* __restrict__ arcs4,
                                                 const unsigned char* __restrict__ UVq,
                                                 const float* __restrict__ scl,
                                                 const float* __restrict__ W2,
                                                 const float* __restrict__ b2,
                                                 float* __restrict__ out) {
    const int tid = threadIdx.x;
    const int sub = tid & 7;
    const int gq = blockIdx.x * 32 + (tid >> 3);
    const int eb = sub * 16;

    float w2v[16], w2s = 0.f;
    #pragma unroll
    for (int i = 0; i < 16; i++) {
        int col = ((i & 7) << 4) + (sub << 1) + (i >> 3);
        w2v[i] = W2[col];
        w2s += w2v[i];
    }
    const float b2s = b2[0];
    const float* sclV = scl + NODES_PAD;

    const long stride = (long)gridDim.x * 64;
    const long limp = (long)(N_ARCS - 2) >> 1;

    long a = (long)gq * 2;
    int4 i0 = arcs4[a >> 1];
    uint4 u0 = *(const uint4*)(UVq + (long)i0.x * 256 + eb);
    uint4 v0 = *(const uint4*)(UVq + (long)i0.y * 256 + 128 + eb);
    uint4 u1 = *(const uint4*)(UVq + (long)i0.z * 256 + eb);
    uint4 v1 = *(const uint4*)(UVq + (long)i0.w * 256 + 128 + eb);
    float sU0 = scl[i0.x], sV0 = sclV[i0.y];
    float sU1 = scl[i0.z], sV1 = sclV[i0.w];
    long p1i = (a + stride) >> 1; if (p1i > limp) p1i = limp;
    int4 i1 = arcs4[p1i];

    while (true) {
        const long an = a + stride;
        uint4 nu0 = *(const uint4*)(UVq + (long)i1.x * 256 + eb);
        uint4 nv0 = *(const uint4*)(UVq + (long)i1.y * 256 + 128 + eb);
        uint4 nu1 = *(const uint4*)(UVq + (long)i1.z * 256 + eb);
        uint4 nv1 = *(const uint4*)(UVq + (long)i1.w * 256 + 128 + eb);
        float nsU0 = scl[i1.x], nsV0 = sclV[i1.y];
        float nsU1 = scl[i1.z], nsV1 = sclV[i1.w];
        long p2i = (an + stride) >> 1; if (p2i > limp) p2i = limp;
        int4 i2 = arcs4[p2i];

        const float r0 = sV0 * __builtin_amdgcn_rcpf(sU0);
        const float r1 = sV1 * __builtin_amdgcn_rcpf(sU1);
        const float C0 = fmaf(128.f, r0, 128.f);
        const float C1 = fmaf(128.f, r1, 128.f);

        float p0 = 0.f, p1 = 0.f;
        const unsigned* uw0 = (const unsigned*)&u0;
        const unsigned* vw0 = (const unsigned*)&v0;
        const unsigned* uw1 = (const unsigned*)&u1;
        const unsigned* vw1 = (const unsigned*)&v1;
        #pragma unroll
        for (int w = 0; w < 4; w++) {
            #pragma unroll
            for (int j = 0; j < 4; j++) {
                float gu0 = (float)((uw0[w] >> (8 * j)) & 0xffu);
                float gv0 = (float)((vw0[w] >> (8 * j)) & 0xffu);
                p0 = fmaf(fmaxf(fmaf(gv0, r0, gu0), C0), w2v[w * 4 + j], p0);
                float gu1 = (float)((uw1[w] >> (8 * j)) & 0xffu);
                float gv1 = (float)((vw1[w] >> (8 * j)) & 0xffu);
                p1 = fmaf(fmaxf(fmaf(gv1, r1, gu1), C1), w2v[w * 4 + j], p1);
            }
        }
        p0 = fmaf(-C0, w2s, p0);
        p1 = fmaf(-C1, w2s, p1);
        #pragma unroll
        for (int o = 4; o >= 1; o >>= 1) {
            p0 += __shfl_xor(p0, o);
            p1 += __shfl_xor(p1, o);
        }
        if (sub == 0) {
            out[a] = fmaf(sU0, p0, b2s);
            out[a + 1] = fmaf(sU1, p1, b2s);
        }

        if (an >= N_ARCS) break;
        a = an;
        u0 = nu0; v0 = nv0; u1 = nu1; v1 = nv1;
        sU0 = nsU0; sV0 = nsV0; sU1 = nsU1; sV1 = nsV1;
        i1 = i2;
    }
}

extern "C" void kernel_launch(void* const* d_in, const int* in_sizes, int n_in,
                              void* d_out, int out_size, void* d_ws, size_t ws_size,
                              hipStream_t stream) {
    const float* z  = (const float*)d_in[0];
    const int4* arcs4 = (const int4*)d_in[1];
    const float* W1 = (const float*)d_in[2];
    const float* b1 = (const float*)d_in[3];
    const float* W2 = (const float*)d_in[4];
    const float* b2 = (const float*)d_in[5];
    float* out = (float*)d_out;

    unsigned char* UVq = (unsigned char*)d_ws;                     // 25.6 MB
    float* scl = (float*)((char*)d_ws + (size_t)NODES_PAD * 256);  // 2*NODES_PAD f32

    hipLaunchKernelGGL(gemm_uv_q, dim3(384, 2), dim3(256), 0, stream,
                       z, W1, b1, UVq, scl);
    hipLaunchKernelGGL(arc_score, dim3(2048), dim3(256), 0, stream,
                       arcs4, UVq, scl, W2, b2, out);
}

// Round 8
// 144.094 us; speedup vs baseline: 1.0541x; 1.0541x over previous
//
#include <hip/hip_runtime.h>
#include <hip/hip_bf16.h>

#define N_NODES 100000
#define NODES_PAD 100096
#define N_ARCS 1000000

typedef __attribute__((ext_vector_type(8))) short bf16x8;
typedef __attribute__((ext_vector_type(4))) float f32x4;

__device__ __forceinline__ unsigned pk2(float lo, float hi) {
    __hip_bfloat162 b = __float22bfloat162_rn(make_float2(lo, hi));
    union { __hip_bfloat162 b; unsigned u; } c; c.b = b; return c.u;
}

__device__ __forceinline__ uint4 pack8(const float4 a, const float4 b) {
    uint4 r;
    r.x = pk2(a.x, a.y);
    r.y = pk2(a.z, a.w);
    r.z = pk2(b.x, b.y);
    r.w = pk2(b.z, b.w);
    return r;
}

// Persistent GEMM + fused int8 row quantization (r6 structure: Bs in LDS,
// 48 KB total -> 3 blocks/CU) + register prefetch of the next A tile so the
// z-load latency hides under K-loop + epilogue instead of the tile boundary.
// y=0: U = z@W1[:,:128]^T + b1 ; y=1: V = z@W1[:,128:]^T.
// UVq rows byte-PERMUTED: byte p of a 128-B half-row holds col (p&7)*16 + (p>>3).
__global__ __launch_bounds__(256) void gemm_uv_q(const float* __restrict__ z,
                                                 const float* __restrict__ W1,
                                                 const float* __restrict__ b1,
                                                 unsigned char* __restrict__ UVq,
                                                 float* __restrict__ scl) {
    __shared__ unsigned short As[64 * 128];    // 16 KB
    __shared__ unsigned short Bs[128 * 128];   // 32 KB
    const int tid = threadIdx.x;
    const int y = blockIdx.y;
    const int c0 = y * 128;
    const int lane = tid & 63;
    const int wave = tid >> 6;
    const int l16 = lane & 15;
    const int quad = lane >> 4;
    const int mstep = gridDim.x * 64;

    // one-time: stage W1-half (swizzled) and the first A tile
    #pragma unroll
    for (int it = 0; it < 8; it++) {
        int i = tid + it * 256;
        int row = i >> 4, g = i & 15;
        const float4* s = (const float4*)(W1 + (long)row * 256 + c0 + g * 8);
        ((uint4*)Bs)[row * 16 + (g ^ (row & 15))] = pack8(s[0], s[1]);
    }
    int m0 = blockIdx.x * 64;
    #pragma unroll
    for (int it = 0; it < 4; it++) {
        int i = tid + it * 256;
        int row = i >> 4, g = i & 15;
        int node = m0 + row;
        uint4 p = make_uint4(0u, 0u, 0u, 0u);
        if (node < N_NODES) {
            const float4* s = (const float4*)(z + (long)node * 128 + g * 8);
            p = pack8(s[0], s[1]);
        }
        ((uint4*)As)[row * 16 + (g ^ (row & 15))] = p;
    }
    __syncthreads();

    float bias[8];
    #pragma unroll
    for (int nt = 0; nt < 8; nt++)
        bias[nt] = (y == 0) ? b1[nt * 16 + l16] : 0.0f;
    float* sclh = scl + (long)y * NODES_PAD;

    while (m0 < N_NODES) {
        const int m1 = m0 + mstep;
        const bool have_next = m1 < N_NODES;

        // issue next tile's global loads NOW; consumed after the epilogue
        float4 ld[8];
        if (have_next) {
            #pragma unroll
            for (int it = 0; it < 4; it++) {
                int i = tid + it * 256;
                int row = i >> 4;
                int g = i & 15;
                int node = m1 + row;
                if (node < N_NODES) {
                    const float4* s = (const float4*)(z + (long)node * 128 + g * 8);
                    ld[it * 2] = s[0];
                    ld[it * 2 + 1] = s[1];
                } else {
                    ld[it * 2] = make_float4(0.f, 0.f, 0.f, 0.f);
                    ld[it * 2 + 1] = make_float4(0.f, 0.f, 0.f, 0.f);
                }
            }
        }

        // K-loop: 4 A ds_reads + 32 B ds_reads + 32 MFMA per wave
        const int arow = wave * 16 + l16;
        f32x4 acc[8] = {};
        #pragma unroll
        for (int ks = 0; ks < 4; ks++) {
            const int gb = ks * 4 + quad;
            const bf16x8 a = *(const bf16x8*)&As[arow * 128 + ((gb ^ l16) << 3)];
            #pragma unroll
            for (int nt = 0; nt < 8; nt++) {
                const bf16x8 b = *(const bf16x8*)&Bs[(nt * 16 + l16) * 128 + ((gb ^ l16) << 3)];
                acc[nt] = __builtin_amdgcn_mfma_f32_16x16x32_bf16(a, b, acc[nt], 0, 0, 0);
            }
        }
        __syncthreads();   // As reads complete before overwrite below

        // epilogue: bias, row absmax (16-lane butterfly), quantize, packed store
        float m[4] = {0.f, 0.f, 0.f, 0.f};
        #pragma unroll
        for (int nt = 0; nt < 8; nt++)
            #pragma unroll
            for (int r = 0; r < 4; r++) {
                acc[nt][r] += bias[nt];
                m[r] = fmaxf(m[r], fabsf(acc[nt][r]));
            }
        #pragma unroll
        for (int o = 1; o <= 8; o <<= 1)
            #pragma unroll
            for (int r = 0; r < 4; r++)
                m[r] = fmaxf(m[r], __shfl_xor(m[r], o));

        const int rbase = m0 + wave * 16 + quad * 4;
        float inv[4];
        #pragma unroll
        for (int r = 0; r < 4; r++) {
            m[r] = fmaxf(m[r], 1e-30f);
            inv[r] = 127.0f * __builtin_amdgcn_rcpf(m[r]);
        }
        if (l16 == 0)
            *(float4*)(sclh + rbase) = make_float4(m[0] * (1.f / 127.f), m[1] * (1.f / 127.f),
                                                   m[2] * (1.f / 127.f), m[3] * (1.f / 127.f));
        #pragma unroll
        for (int r = 0; r < 4; r++) {
            unsigned lo = 0, hi = 0;
            #pragma unroll
            for (int nt = 0; nt < 4; nt++) {
                unsigned q = (unsigned)__float2int_rn(fmaf(acc[nt][r], inv[r], 128.f));
                lo |= (q & 0xffu) << (8 * nt);
            }
            #pragma unroll
            for (int nt = 4; nt < 8; nt++) {
                unsigned q = (unsigned)__float2int_rn(fmaf(acc[nt][r], inv[r], 128.f));
                hi |= (q & 0xffu) << (8 * (nt - 4));
            }
            *(uint2*)(UVq + (long)(rbase + r) * 256 + c0 + l16 * 8) = make_uint2(lo, hi);
        }

        // write prefetched tile into As (loads have had K-loop+epilogue to land)
        if (have_next) {
            #pragma unroll
            for (int it = 0; it < 4; it++) {
                int i = tid + it * 256;
                int row = i >> 4, g = i & 15;
                ((uint4*)As)[row * 16 + (g ^ (row & 15))] =
                    pack8(ld[it * 2], ld[it * 2 + 1]);
            }
        }
        __syncthreads();   // As writes visible before next K-loop
        m0 = m1;
    }
}

// One arc-pair per 8-lane group (uint4 = 16 elems/lane), software-pipelined.
// relu trick: out = sU*(sum_j max(h_j, C)*w2_j - C*sumW2) + b2,
// h_j = gu_j + r*gv_j, r = sV/sU, C = 128*(1+r).
__global__ __launch_bounds__(256) void arc_score(const int4* __restrict__ arcs4,
                                                 const unsigned char* __restrict__ UVq,
                                                 const float* __restrict__ scl,
                                                 const float* __restrict__ W2,
                                                 const float* __restrict__ b2,
                                                 float* __restrict__ out) {
    const int tid = threadIdx.x;
    const int sub = tid & 7;
    const int gq = blockIdx.x * 32 + (tid >> 3);
    const int eb = sub * 16;

    float w2v[16], w2s = 0.f;
    #pragma unroll
    for (int i = 0; i < 16; i++) {
        int col = ((i & 7) << 4) + (sub << 1) + (i >> 3);
        w2v[i] = W2[col];
        w2s += w2v[i];
    }
    const float b2s = b2[0];
    const float* sclV = scl + NODES_PAD;

    const long stride = (long)gridDim.x * 64;
    const long limp = (long)(N_ARCS - 2) >> 1;

    long a = (long)gq * 2;
    int4 i0 = arcs4[a >> 1];
    uint4 u0 = *(const uint4*)(UVq + (long)i0.x * 256 + eb);
    uint4 v0 = *(const uint4*)(UVq + (long)i0.y * 256 + 128 + eb);
    uint4 u1 = *(const uint4*)(UVq + (long)i0.z * 256 + eb);
    uint4 v1 = *(const uint4*)(UVq + (long)i0.w * 256 + 128 + eb);
    float sU0 = scl[i0.x], sV0 = sclV[i0.y];
    float sU1 = scl[i0.z], sV1 = sclV[i0.w];
    long p1i = (a + stride) >> 1; if (p1i > limp) p1i = limp;
    int4 i1 = arcs4[p1i];

    while (true) {
        const long an = a + stride;
        uint4 nu0 = *(const uint4*)(UVq + (long)i1.x * 256 + eb);
        uint4 nv0 = *(const uint4*)(UVq + (long)i1.y * 256 + 128 + eb);
        uint4 nu1 = *(const uint4*)(UVq + (long)i1.z * 256 + eb);
        uint4 nv1 = *(const uint4*)(UVq + (long)i1.w * 256 + 128 + eb);
        float nsU0 = scl[i1.x], nsV0 = sclV[i1.y];
        float nsU1 = scl[i1.z], nsV1 = sclV[i1.w];
        long p2i = (an + stride) >> 1; if (p2i > limp) p2i = limp;
        int4 i2 = arcs4[p2i];

        const float r0 = sV0 * __builtin_amdgcn_rcpf(sU0);
        const float r1 = sV1 * __builtin_amdgcn_rcpf(sU1);
        const float C0 = fmaf(128.f, r0, 128.f);
        const float C1 = fmaf(128.f, r1, 128.f);

        float p0 = 0.f, p1 = 0.f;
        const unsigned* uw0 = (const unsigned*)&u0;
        const unsigned* vw0 = (const unsigned*)&v0;
        const unsigned* uw1 = (const unsigned*)&u1;
        const unsigned* vw1 = (const unsigned*)&v1;
        #pragma unroll
        for (int w = 0; w < 4; w++) {
            #pragma unroll
            for (int j = 0; j < 4; j++) {
                float gu0 = (float)((uw0[w] >> (8 * j)) & 0xffu);
                float gv0 = (float)((vw0[w] >> (8 * j)) & 0xffu);
                p0 = fmaf(fmaxf(fmaf(gv0, r0, gu0), C0), w2v[w * 4 + j], p0);
                float gu1 = (float)((uw1[w] >> (8 * j)) & 0xffu);
                float gv1 = (float)((vw1[w] >> (8 * j)) & 0xffu);
                p1 = fmaf(fmaxf(fmaf(gv1, r1, gu1), C1), w2v[w * 4 + j], p1);
            }
        }
        p0 = fmaf(-C0, w2s, p0);
        p1 = fmaf(-C1, w2s, p1);
        #pragma unroll
        for (int o = 4; o >= 1; o >>= 1) {
            p0 += __shfl_xor(p0, o);
            p1 += __shfl_xor(p1, o);
        }
        if (sub == 0) {
            out[a] = fmaf(sU0, p0, b2s);
            out[a + 1] = fmaf(sU1, p1, b2s);
        }

        if (an >= N_ARCS) break;
        a = an;
        u0 = nu0; v0 = nv0; u1 = nu1; v1 = nv1;
        sU0 = nsU0; sV0 = nsV0; sU1 = nsU1; sV1 = nsV1;
        i1 = i2;
    }
}

extern "C" void kernel_launch(void* const* d_in, const int* in_sizes, int n_in,
                              void* d_out, int out_size, void* d_ws, size_t ws_size,
                              hipStream_t stream) {
    const float* z  = (const float*)d_in[0];
    const int4* arcs4 = (const int4*)d_in[1];
    const float* W1 = (const float*)d_in[2];
    const float* b1 = (const float*)d_in[3];
    const float* W2 = (const float*)d_in[4];
    const float* b2 = (const float*)d_in[5];
    float* out = (float*)d_out;

    unsigned char* UVq = (unsigned char*)d_ws;                     // 25.6 MB
    float* scl = (float*)((char*)d_ws + (size_t)NODES_PAD * 256);  // 2*NODES_PAD f32

    hipLaunchKernelGGL(gemm_uv_q, dim3(384, 2), dim3(256), 0, stream,
                       z, W1, b1, UVq, scl);
    hipLaunchKernelGGL(arc_score, dim3(2048), dim3(256), 0, stream,
                       arcs4, UVq, scl, W2, b2, out);
}